// Round 17
// baseline (656.663 us; speedup 1.0000x reference)
//
#include <hip/hip_runtime.h>
#include <hip/hip_bf16.h>

// Established facts (R3-R16): d_in = setup_inputs() dict order; floats fp32;
// edges int32; output fp32 [20000,128]. R16=615.7us, absmax 4.88e-4 (bf16 f).
// R16 lesson: 64-thread workgroups hit the per-CU workgroup-slot limit ->
// occupancy 40%. This round: same per-wave math, but 2 nodes/tiles per
// 128-thread block (wave-private LDS slices) to restore occupancy.
#define NN 20000
#define RR 3
#define EE 320000
#define FD 128
#define AH 32
#define NP1 (NN + 1)
#define NEG_SLOPE 0.2f

__device__ __forceinline__ int clamp_idx(int v) {
  v = v < 0 ? 0 : v;
  return v < NN ? v : NN - 1;
}
__device__ __forceinline__ float leaky_exp(float e) {
  e = e > 0.f ? e : NEG_SLOPE * e;
  return __expf(e);
}
__device__ __forceinline__ float bf2f(unsigned short u) {
  union { unsigned int i; float f; } c;
  c.i = ((unsigned int)u) << 16;
  return c.f;
}
// fp32 -> bf16 round-to-nearest-even
__device__ __forceinline__ unsigned short f2bf(float v) {
  union { float f; unsigned int i; } c;
  c.f = v;
  const unsigned int u = c.i;
  return (unsigned short)((u + 0x7fffu + ((u >> 16) & 1u)) >> 16);
}

// ----------------------------- CSR build -----------------------------------
__global__ void csr_count(const int* __restrict__ edg, int* __restrict__ cnt) {
  const int idx = blockIdx.x * blockDim.x + threadIdx.x;
  if (idx >= RR * EE) return;
  const int r = idx / EE, k = idx - r * EE;
  const int dst = clamp_idx(edg[(size_t)r * 2 * EE + EE + k]);
  atomicAdd(&cnt[r * NN + dst], 1);
}

__global__ void csr_scan(const int* __restrict__ cnt, int* __restrict__ starts,
                         int* __restrict__ cursor) {
  __shared__ int part[256];
  const int r = blockIdx.x, t = threadIdx.x;
  const int CH = (NN + 255) / 256;  // 79
  const int lo = t * CH, hi = min(lo + CH, NN);
  int s = 0;
  for (int i = lo; i < hi; ++i) s += cnt[r * NN + i];
  part[t] = s;
  __syncthreads();
  if (t == 0) {
    int run = 0;
    for (int i = 0; i < 256; ++i) { const int v = part[i]; part[i] = run; run += v; }
  }
  __syncthreads();
  int run = part[t];
  for (int i = lo; i < hi; ++i) {
    starts[r * NP1 + i] = run;
    cursor[r * NP1 + i] = run;
    run += cnt[r * NN + i];
  }
  if (t == 255) starts[r * NP1 + NN] = run;
}

__global__ void csr_scatter(const int* __restrict__ edg, int* __restrict__ cursor,
                            int* __restrict__ csrsrc) {
  const int idx = blockIdx.x * blockDim.x + threadIdx.x;
  if (idx >= RR * EE) return;
  const int r = idx / EE, k = idx - r * EE;
  const int src = clamp_idx(edg[(size_t)r * 2 * EE + k]);
  const int dst = clamp_idx(edg[(size_t)r * 2 * EE + EE + k]);
  const int pos = atomicAdd(&cursor[r * NP1 + dst], 1);
  csrsrc[(size_t)r * EE + pos] = src;
}

// ---------------------------------------------------------------------------
// Merged gemm: 128-thread block = 2 waves, each wave one BN=16 tile.
// Per-wave: thread j owns cols j (head 0), j+64 (head 1); el/er via shfl.
// ---------------------------------------------------------------------------
#define BN 16
__global__ void __launch_bounds__(128, 4) gemm_all(
    const float* __restrict__ hin,            // [N,128]
    const float* __restrict__ W,              // [3,128,128]
    const float* __restrict__ al,             // [3,128]
    const float* __restrict__ ar,             // [3,128]
    unsigned short* __restrict__ fb,          // [3,N,128] bf16
    float* __restrict__ el,                   // [3,N,2]
    float* __restrict__ er) {
  __shared__ float lh[2][BN * FD];  // 16 KB
  const int g = threadIdx.x >> 6;   // wave id 0..1
  const int j = threadIdx.x & 63;   // lane
  const int tile = blockIdx.x * 2 + g;       // 0..3749
  const int blocksPerRel = NN / BN;          // 1250
  const int r = tile / blocksPerRel;
  const int n0 = (tile % blocksPerRel) * BN;

  {
    const float4* s4 = (const float4*)&hin[(size_t)n0 * FD];
    float4* d4 = (float4*)lh[g];
#pragma unroll
    for (int t = 0; t < 8; ++t) d4[j + 64 * t] = s4[j + 64 * t];
  }
  __syncthreads();

  const float* Wr = W + (size_t)r * FD * FD;
  float acc0[BN], acc1[BN];
#pragma unroll
  for (int i = 0; i < BN; ++i) { acc0[i] = 0.f; acc1[i] = 0.f; }

  for (int k4 = 0; k4 < FD; k4 += 4) {
    const float wa0 = Wr[(size_t)(k4 + 0) * FD + j];
    const float wb0 = Wr[(size_t)(k4 + 0) * FD + j + 64];
    const float wa1 = Wr[(size_t)(k4 + 1) * FD + j];
    const float wb1 = Wr[(size_t)(k4 + 1) * FD + j + 64];
    const float wa2 = Wr[(size_t)(k4 + 2) * FD + j];
    const float wb2 = Wr[(size_t)(k4 + 2) * FD + j + 64];
    const float wa3 = Wr[(size_t)(k4 + 3) * FD + j];
    const float wb3 = Wr[(size_t)(k4 + 3) * FD + j + 64];
#pragma unroll
    for (int i = 0; i < BN; ++i) {
      const float4 h4 = *(const float4*)&lh[g][i * FD + k4];
      acc0[i] = fmaf(h4.x, wa0, fmaf(h4.y, wa1, fmaf(h4.z, wa2, fmaf(h4.w, wa3, acc0[i]))));
      acc1[i] = fmaf(h4.x, wb0, fmaf(h4.y, wb1, fmaf(h4.z, wb2, fmaf(h4.w, wb3, acc1[i]))));
    }
  }

  const float al0 = al[r * FD + j];
  const float al1v = al[r * FD + j + 64];
  const float ar0 = ar[r * FD + j];
  const float ar1v = ar[r * FD + j + 64];

#pragma unroll
  for (int i = 0; i < BN; ++i) {
    const size_t row = ((size_t)r * NN + n0 + i) * FD;
    fb[row + j] = f2bf(acc0[i]);
    fb[row + j + 64] = f2bf(acc1[i]);
    float e0 = acc0[i] * al0;
    float e1 = acc1[i] * al1v;
    float u0 = acc0[i] * ar0;
    float u1 = acc1[i] * ar1v;
#pragma unroll
    for (int off = 32; off > 0; off >>= 1) {
      e0 += __shfl_down(e0, off, 64);
      e1 += __shfl_down(e1, off, 64);
      u0 += __shfl_down(u0, off, 64);
      u1 += __shfl_down(u1, off, 64);
    }
    if (j == 0) {
      const size_t base = ((size_t)r * NN + n0 + i) * 2;
      el[base + 0] = e0;
      el[base + 1] = e1;
      er[base + 0] = u0;
      er[base + 1] = u1;
    }
  }
}

// ---------------------------------------------------------------------------
// Fused pull + semantic logit: 128-thread block = 2 waves, each wave one
// (r,n). Lane j owns cols 2j,2j+1 (head h=j>>5); f gathered as bf16x2.
// Per-column accumulation order unchanged (bitwise = R16).
// ---------------------------------------------------------------------------
__global__ void __launch_bounds__(128, 4) pull_semw(
    const int* __restrict__ starts,   // [3,NP1]
    const int* __restrict__ csrsrc,   // [3,E]
    const float* __restrict__ el,     // [3,N,2]
    const float* __restrict__ er,
    const unsigned short* __restrict__ fb,  // [3,N,128] bf16
    const float* __restrict__ b,      // [3,128]
    int do_relu,
    const float* __restrict__ aw1,    // [128,32]
    const float* __restrict__ ab1,    // [32]
    const float* __restrict__ aw2,    // [32]
    float* __restrict__ z,            // [3,N,128]
    float* __restrict__ wv) {         // [3,N]
  __shared__ float lz[2][FD];
  __shared__ float red[2][4][AH];
  __shared__ float wcol[2][AH];
  const int g = threadIdx.x >> 6;       // wave id
  const int j = threadIdx.x & 63;       // lane
  const int rn = blockIdx.x * 2 + g;    // 0..59999
  const int r = rn / NN;
  const int n = rn - r * NN;
  const int c = j * 2;
  const int h = j >> 5;
  const int* st = starts + r * NP1;
  const int* cs = csrsrc + (size_t)r * EE;
  const float* elr = el + (size_t)r * NN * 2;
  const unsigned short* fr = fb + (size_t)r * NN * FD;
  const int s0 = st[n], s1 = st[n + 1];
  const float ern = er[((size_t)r * NN + n) * 2 + h];

  float ax = 0.f, ay = 0.f, den = 0.f;
  int p = s0;
#define EDGE(iK)                                                        \
  {                                                                     \
    const int sK = cs[p + iK];                                          \
    const float wK = leaky_exp(elr[(size_t)sK * 2 + h] + ern);          \
    const unsigned int fvK = *(const unsigned int*)&fr[(size_t)sK * FD + c]; \
    den += wK;                                                          \
    ax += wK * bf2f((unsigned short)(fvK & 0xffff));                    \
    ay += wK * bf2f((unsigned short)(fvK >> 16));                       \
  }
  for (; p + 8 <= s1; p += 8) {
    EDGE(0) EDGE(1) EDGE(2) EDGE(3) EDGE(4) EDGE(5) EDGE(6) EDGE(7)
  }
  for (; p + 4 <= s1; p += 4) {
    EDGE(0) EDGE(1) EDGE(2) EDGE(3)
  }
  for (; p < s1; ++p) {
    EDGE(0)
  }
#undef EDGE

  const float inv = 1.f / fmaxf(den, 1e-9f);
  float vx = ax * inv + b[r * FD + c];
  float vy = ay * inv + b[r * FD + c + 1];
  if (do_relu) { vx = fmaxf(vx, 0.f); vy = fmaxf(vy, 0.f); }
  float2* zrow = (float2*)&z[(size_t)rn * FD];
  zrow[j] = make_float2(vx, vy);

  // ---- fused semantic-attention logit (wave-private LDS slice) ----
  lz[g][c] = vx;
  lz[g][c + 1] = vy;
  __syncthreads();
  const int col = j & 31;
  const int p0 = j >> 5;  // 0..1; also handles p0+2
#pragma unroll
  for (int t = 0; t < 2; ++t) {
    const int part = p0 + 2 * t;
    float a2 = 0.f;
#pragma unroll
    for (int kk = 0; kk < 32; ++kk) {
      const int k = part * 32 + kk;
      a2 += lz[g][k] * aw1[(size_t)k * AH + col];
    }
    red[g][part][col] = a2;
  }
  __syncthreads();
  if (j < 32)
    wcol[g][j] = tanhf(red[g][0][j] + red[g][1][j] + red[g][2][j] +
                       red[g][3][j] + ab1[j]) * aw2[j];
  __syncthreads();
  if (j == 0) {
    float w = 0.f;
#pragma unroll
    for (int cix = 0; cix < AH; ++cix) w += wcol[g][cix];
    wv[rn] = w;
  }
}

// Fused reduce + beta
__global__ void reduce_beta(const float* __restrict__ wv, float* __restrict__ S) {
  __shared__ float p[256];
  const int t = threadIdx.x;
  float tot[RR];
  for (int r = 0; r < RR; ++r) {
    float s = 0.f;
    for (int n = t; n < NN; n += 256) s += wv[(size_t)r * NN + n];
    p[t] = s;
    __syncthreads();
    for (int off = 128; off > 0; off >>= 1) {
      if (t < off) p[t] += p[t + off];
      __syncthreads();
    }
    tot[r] = p[0];
    __syncthreads();
  }
  if (t == 0) {
    S[0] = tot[0]; S[1] = tot[1]; S[2] = tot[2];
    float w0 = tot[0] / (float)NN, w1 = tot[1] / (float)NN, w2 = tot[2] / (float)NN;
    float mx = fmaxf(w0, fmaxf(w1, w2));
    float e0 = __expf(w0 - mx), e1 = __expf(w1 - mx), e2 = __expf(w2 - mx);
    float inv = 1.f / (e0 + e1 + e2);
    S[4] = e0 * inv; S[5] = e1 * inv; S[6] = e2 * inv;
  }
}

__global__ void combine_f32(const float* __restrict__ z,
                            const float* __restrict__ S,
                            float* __restrict__ out) {
  const int idx = blockIdx.x * blockDim.x + threadIdx.x;
  if (idx >= NN * FD) return;
  out[idx] = S[4] * z[idx] + S[5] * z[(size_t)NN * FD + idx] +
             S[6] * z[2 * (size_t)NN * FD + idx];
}

// ------------------- fallback kernels (R10 CSR path, proven) ----------------
__global__ void gemm_el_er(const float* __restrict__ hin,
                           const float* __restrict__ W,
                           const float* __restrict__ al,
                           const float* __restrict__ ar,
                           float* __restrict__ f,
                           float* __restrict__ el,
                           float* __restrict__ er) {
  const int B8 = 8;
  __shared__ float lh[B8 * FD];
  const int j = threadIdx.x;
  const int n0 = blockIdx.x * B8;
#pragma unroll
  for (int i = 0; i < B8; ++i)
    lh[i * FD + j] = hin[(size_t)(n0 + i) * FD + j];
  __syncthreads();
  float acc[B8];
#pragma unroll
  for (int i = 0; i < B8; ++i) acc[i] = 0.f;
  for (int k = 0; k < FD; ++k) {
    const float w = W[(size_t)k * FD + j];
#pragma unroll
    for (int i = 0; i < B8; ++i) acc[i] += lh[i * FD + k] * w;
  }
  const float alv = al[j];
  const float arv = ar[j];
#pragma unroll
  for (int i = 0; i < B8; ++i) f[(size_t)(n0 + i) * FD + j] = acc[i];
  __syncthreads();
#pragma unroll
  for (int i = 0; i < B8; ++i) lh[i * FD + j] = acc[i] * alv;
  __syncthreads();
  if (j < B8 * 2) {
    const int i = j >> 1, h = j & 1;
    const float* p = &lh[i * FD + h * 64];
    float s = 0.f;
    for (int d = 0; d < 64; ++d) s += p[d];
    el[(size_t)(n0 + i) * 2 + h] = s;
  }
  __syncthreads();
#pragma unroll
  for (int i = 0; i < B8; ++i) lh[i * FD + j] = acc[i] * arv;
  __syncthreads();
  if (j < B8 * 2) {
    const int i = j >> 1, h = j & 1;
    const float* p = &lh[i * FD + h * 64];
    float s = 0.f;
    for (int d = 0; d < 64; ++d) s += p[d];
    er[(size_t)(n0 + i) * 2 + h] = s;
  }
}

__global__ void pull_aggr(const int* __restrict__ starts,
                          const int* __restrict__ csrsrc,
                          const float* __restrict__ el,
                          const float* __restrict__ er,
                          const float* __restrict__ f,
                          const float* __restrict__ b,
                          int do_relu,
                          float* __restrict__ z) {
  const int n = blockIdx.x;
  const int j = threadIdx.x;
  const int h = j >> 6;
  const int s0 = starts[n], s1 = starts[n + 1];
  const float ern = er[(size_t)n * 2 + h];
  float acc = 0.f, den = 0.f;
  for (int p = s0; p < s1; ++p) {
    const int src = csrsrc[p];
    const float w = leaky_exp(el[(size_t)src * 2 + h] + ern);
    den += w;
    acc += w * f[(size_t)src * FD + j];
  }
  float v = acc / fmaxf(den, 1e-9f) + b[j];
  if (do_relu) v = fmaxf(v, 0.f);
  z[(size_t)n * FD + j] = v;
}

__global__ void semw_nodes(const float* __restrict__ z,
                           const float* __restrict__ aw1,
                           const float* __restrict__ ab1,
                           const float* __restrict__ aw2,
                           float* __restrict__ wv) {
  __shared__ float lz[2][FD];
  __shared__ float red[2][4][AH];
  __shared__ float wcol[2][AH];
  const int g = threadIdx.x >> 7;
  const int t = threadIdx.x & 127;
  const int pair = blockIdx.x * 2 + g;
  const int n = pair / RR;
  const int r = pair - n * RR;
  lz[g][t] = z[((size_t)r * NN + n) * FD + t];
  __syncthreads();
  const int col = t & 31;
  const int part = t >> 5;
  float acc = 0.f;
#pragma unroll
  for (int kk = 0; kk < 32; ++kk) {
    const int k = part * 32 + kk;
    acc += lz[g][k] * aw1[(size_t)k * AH + col];
  }
  red[g][part][col] = acc;
  __syncthreads();
  if (part == 0) {
    float s = red[g][0][col] + red[g][1][col] + red[g][2][col] + red[g][3][col];
    wcol[g][col] = tanhf(s + ab1[col]) * aw2[col];
  }
  __syncthreads();
  if (t == 0) {
    float w = 0.f;
#pragma unroll
    for (int c = 0; c < AH; ++c) w += wcol[g][c];
    wv[(size_t)r * NN + n] = w;
  }
}

// ---------------------------------------------------------------------------
extern "C" void kernel_launch(void* const* d_in, const int* in_sizes, int n_in,
                              void* d_out, int out_size, void* d_ws, size_t ws_size,
                              hipStream_t stream) {
  const float* x   = (const float*)d_in[0];
  const int*   edg = (const int*)d_in[1];
  const float* W1  = (const float*)d_in[2];
  const float* al1 = (const float*)d_in[3];
  const float* ar1 = (const float*)d_in[4];
  const float* b1  = (const float*)d_in[5];
  const float* W2  = (const float*)d_in[6];
  const float* al2 = (const float*)d_in[7];
  const float* ar2 = (const float*)d_in[8];
  const float* b2  = (const float*)d_in[9];
  const float* aw1 = (const float*)d_in[10];
  const float* ab1 = (const float*)d_in[11];
  const float* aw2 = (const float*)d_in[12];
  const float* bw1 = (const float*)d_in[13];
  const float* bb1 = (const float*)d_in[14];
  const float* bw2 = (const float*)d_in[15];
  float* out = (float*)d_out;

  const size_t need_big = 67200128;  // gate proven on this ws
  if (ws_size >= need_big) {
    float* S      = (float*)d_ws;                    // 16
    float* wv     = S + 16;                          // RR*NN
    float* el     = wv + (size_t)RR * NN;            // RR*NN*2
    float* er     = el + (size_t)RR * NN * 2;        // RR*NN*2
    float* z      = er + (size_t)RR * NN * 2;        // RR*NN*FD fp32
    unsigned short* fb = (unsigned short*)(z + (size_t)RR * NN * FD);  // bf16
    int*   cnt    = (int*)(fb + (size_t)RR * NN * FD);  // RR*NN
    int*   starts = cnt + RR * NN;                   // RR*NP1
    int*   cursor = starts + RR * NP1;               // RR*NP1
    int*   csrsrc = cursor + RR * NP1;               // RR*EE

    hipMemsetAsync(cnt, 0, (size_t)RR * NN * sizeof(int), stream);
    csr_count<<<(RR * EE + 255) / 256, 256, 0, stream>>>(edg, cnt);
    csr_scan<<<RR, 256, 0, stream>>>(cnt, starts, cursor);
    csr_scatter<<<(RR * EE + 255) / 256, 256, 0, stream>>>(edg, cursor, csrsrc);

    // layer 1
    gemm_all<<<RR * (NN / BN) / 2, 128, 0, stream>>>(x, W1, al1, ar1, fb, el, er);
    pull_semw<<<RR * NN / 2, 128, 0, stream>>>(starts, csrsrc, el, er, fb, b1, 1,
                                               aw1, ab1, aw2, z, wv);
    reduce_beta<<<1, 256, 0, stream>>>(wv, S);
    combine_f32<<<(NN * FD + 255) / 256, 256, 0, stream>>>(z, S, out);  // hmid

    // layer 2
    gemm_all<<<RR * (NN / BN) / 2, 128, 0, stream>>>(out, W2, al2, ar2, fb, el, er);
    pull_semw<<<RR * NN / 2, 128, 0, stream>>>(starts, csrsrc, el, er, fb, b2, 0,
                                               bw1, bb1, bw2, z, wv);
    reduce_beta<<<1, 256, 0, stream>>>(wv, S);
    combine_f32<<<(NN * FD + 255) / 256, 256, 0, stream>>>(z, S, out);
    return;
  }

  // ---------------- fallback: R10 CSR path (46 MB, proven) ----------------
  float* S      = (float*)d_ws;
  float* wv     = S + 16;
  float* el     = wv + (size_t)RR * NN;
  float* er     = el + (size_t)NN * 2;
  float* f      = er + (size_t)NN * 2;
  float* z      = f + (size_t)NN * FD;
  int*   cnt    = (int*)(z + (size_t)RR * NN * FD);
  int*   starts = cnt + RR * NN;
  int*   cursor = starts + RR * NP1;
  int*   csrsrc = cursor + RR * NP1;

  hipMemsetAsync(cnt, 0, (size_t)RR * NN * sizeof(int), stream);
  csr_count<<<(RR * EE + 255) / 256, 256, 0, stream>>>(edg, cnt);
  csr_scan<<<RR, 256, 0, stream>>>(cnt, starts, cursor);
  csr_scatter<<<(RR * EE + 255) / 256, 256, 0, stream>>>(edg, cursor, csrsrc);

  for (int r = 0; r < RR; ++r) {
    gemm_el_er<<<NN / 8, 128, 0, stream>>>(
        x, W1 + (size_t)r * FD * FD, al1 + r * FD, ar1 + r * FD, f, el, er);
    pull_aggr<<<NN, 128, 0, stream>>>(starts + r * NP1, csrsrc + (size_t)r * EE,
                                      el, er, f, b1 + r * FD, 1,
                                      z + (size_t)r * NN * FD);
  }
  semw_nodes<<<NN * RR / 2, 256, 0, stream>>>(z, aw1, ab1, aw2, wv);
  reduce_beta<<<1, 256, 0, stream>>>(wv, S);
  combine_f32<<<(NN * FD + 255) / 256, 256, 0, stream>>>(z, S, out);

  for (int r = 0; r < RR; ++r) {
    gemm_el_er<<<NN / 8, 128, 0, stream>>>(
        out, W2 + (size_t)r * FD * FD, al2 + r * FD, ar2 + r * FD, f, el, er);
    pull_aggr<<<NN, 128, 0, stream>>>(starts + r * NP1, csrsrc + (size_t)r * EE,
                                      el, er, f, b2 + r * FD, 0,
                                      z + (size_t)r * NN * FD);
  }
  semw_nodes<<<NN * RR / 2, 256, 0, stream>>>(z, bw1, bb1, bw2, wv);
  reduce_beta<<<1, 256, 0, stream>>>(wv, S);
  combine_f32<<<(NN * FD + 255) / 256, 256, 0, stream>>>(z, S, out);
}

// Round 18
// 651.888 us; speedup vs baseline: 1.0073x; 1.0073x over previous
//
#include <hip/hip_runtime.h>
#include <hip/hip_bf16.h>

// Established facts (R3-R17): d_in = setup_inputs() dict order; floats fp32;
// edges int32; output fp32 [20000,128]. Best = R16 615.7us (64-thr waves,
// bf16 f, occupancy 40%). R17 lesson: barrier-coupled 2-wave blocks lose to
// degree skew; slots limit independent wave-streams to ~16/CU. This round:
// 256-thr blocks = 4 INDEPENDENT waves (wave-private LDS slices, no
// __syncthreads; __builtin_amdgcn_wave_barrier pins DS order within a wave).
#define NN 20000
#define RR 3
#define EE 320000
#define FD 128
#define AH 32
#define NP1 (NN + 1)
#define NEG_SLOPE 0.2f

__device__ __forceinline__ int clamp_idx(int v) {
  v = v < 0 ? 0 : v;
  return v < NN ? v : NN - 1;
}
__device__ __forceinline__ float leaky_exp(float e) {
  e = e > 0.f ? e : NEG_SLOPE * e;
  return __expf(e);
}
__device__ __forceinline__ float bf2f(unsigned short u) {
  union { unsigned int i; float f; } c;
  c.i = ((unsigned int)u) << 16;
  return c.f;
}
// fp32 -> bf16 round-to-nearest-even
__device__ __forceinline__ unsigned short f2bf(float v) {
  union { float f; unsigned int i; } c;
  c.f = v;
  const unsigned int u = c.i;
  return (unsigned short)((u + 0x7fffu + ((u >> 16) & 1u)) >> 16);
}

// ----------------------------- CSR build -----------------------------------
__global__ void csr_count(const int* __restrict__ edg, int* __restrict__ cnt) {
  const int idx = blockIdx.x * blockDim.x + threadIdx.x;
  if (idx >= RR * EE) return;
  const int r = idx / EE, k = idx - r * EE;
  const int dst = clamp_idx(edg[(size_t)r * 2 * EE + EE + k]);
  atomicAdd(&cnt[r * NN + dst], 1);
}

__global__ void csr_scan(const int* __restrict__ cnt, int* __restrict__ starts,
                         int* __restrict__ cursor) {
  __shared__ int part[256];
  const int r = blockIdx.x, t = threadIdx.x;
  const int CH = (NN + 255) / 256;  // 79
  const int lo = t * CH, hi = min(lo + CH, NN);
  int s = 0;
  for (int i = lo; i < hi; ++i) s += cnt[r * NN + i];
  part[t] = s;
  __syncthreads();
  if (t == 0) {
    int run = 0;
    for (int i = 0; i < 256; ++i) { const int v = part[i]; part[i] = run; run += v; }
  }
  __syncthreads();
  int run = part[t];
  for (int i = lo; i < hi; ++i) {
    starts[r * NP1 + i] = run;
    cursor[r * NP1 + i] = run;
    run += cnt[r * NN + i];
  }
  if (t == 255) starts[r * NP1 + NN] = run;
}

__global__ void csr_scatter(const int* __restrict__ edg, int* __restrict__ cursor,
                            int* __restrict__ csrsrc) {
  const int idx = blockIdx.x * blockDim.x + threadIdx.x;
  if (idx >= RR * EE) return;
  const int r = idx / EE, k = idx - r * EE;
  const int src = clamp_idx(edg[(size_t)r * 2 * EE + k]);
  const int dst = clamp_idx(edg[(size_t)r * 2 * EE + EE + k]);
  const int pos = atomicAdd(&cursor[r * NP1 + dst], 1);
  csrsrc[(size_t)r * EE + pos] = src;
}

// ---------------------------------------------------------------------------
// Merged gemm: 256-thread block = 4 INDEPENDENT waves, one BN=16 tile each.
// Wave-private LDS slice; no __syncthreads (DS ops per-wave are in-order;
// wave_barrier pins compiler ordering). Lane j owns cols j / j+64.
// ---------------------------------------------------------------------------
#define BN 16
__global__ void __launch_bounds__(256) gemm_all(
    const float* __restrict__ hin,            // [N,128]
    const float* __restrict__ W,              // [3,128,128]
    const float* __restrict__ al,             // [3,128]
    const float* __restrict__ ar,             // [3,128]
    unsigned short* __restrict__ fb,          // [3,N,128] bf16
    float* __restrict__ el,                   // [3,N,2]
    float* __restrict__ er) {
  __shared__ float lh[4][BN * FD];  // 32 KB
  const int g = threadIdx.x >> 6;   // wave 0..3
  const int j = threadIdx.x & 63;   // lane
  const int tile = blockIdx.x * 4 + g;
  const int blocksPerRel = NN / BN;          // 1250
  if (tile >= RR * blocksPerRel) return;     // wave-granular guard (no barriers)
  const int r = tile / blocksPerRel;
  const int n0 = (tile % blocksPerRel) * BN;

  {
    const float4* s4 = (const float4*)&hin[(size_t)n0 * FD];
    float4* d4 = (float4*)lh[g];
#pragma unroll
    for (int t = 0; t < 8; ++t) d4[j + 64 * t] = s4[j + 64 * t];
  }
  __builtin_amdgcn_wave_barrier();

  const float* Wr = W + (size_t)r * FD * FD;
  float acc0[BN], acc1[BN];
#pragma unroll
  for (int i = 0; i < BN; ++i) { acc0[i] = 0.f; acc1[i] = 0.f; }

  for (int k4 = 0; k4 < FD; k4 += 4) {
    const float wa0 = Wr[(size_t)(k4 + 0) * FD + j];
    const float wb0 = Wr[(size_t)(k4 + 0) * FD + j + 64];
    const float wa1 = Wr[(size_t)(k4 + 1) * FD + j];
    const float wb1 = Wr[(size_t)(k4 + 1) * FD + j + 64];
    const float wa2 = Wr[(size_t)(k4 + 2) * FD + j];
    const float wb2 = Wr[(size_t)(k4 + 2) * FD + j + 64];
    const float wa3 = Wr[(size_t)(k4 + 3) * FD + j];
    const float wb3 = Wr[(size_t)(k4 + 3) * FD + j + 64];
#pragma unroll
    for (int i = 0; i < BN; ++i) {
      const float4 h4 = *(const float4*)&lh[g][i * FD + k4];
      acc0[i] = fmaf(h4.x, wa0, fmaf(h4.y, wa1, fmaf(h4.z, wa2, fmaf(h4.w, wa3, acc0[i]))));
      acc1[i] = fmaf(h4.x, wb0, fmaf(h4.y, wb1, fmaf(h4.z, wb2, fmaf(h4.w, wb3, acc1[i]))));
    }
  }

  const float al0 = al[r * FD + j];
  const float al1v = al[r * FD + j + 64];
  const float ar0 = ar[r * FD + j];
  const float ar1v = ar[r * FD + j + 64];

#pragma unroll
  for (int i = 0; i < BN; ++i) {
    const size_t row = ((size_t)r * NN + n0 + i) * FD;
    fb[row + j] = f2bf(acc0[i]);
    fb[row + j + 64] = f2bf(acc1[i]);
    float e0 = acc0[i] * al0;
    float e1 = acc1[i] * al1v;
    float u0 = acc0[i] * ar0;
    float u1 = acc1[i] * ar1v;
#pragma unroll
    for (int off = 32; off > 0; off >>= 1) {
      e0 += __shfl_down(e0, off, 64);
      e1 += __shfl_down(e1, off, 64);
      u0 += __shfl_down(u0, off, 64);
      u1 += __shfl_down(u1, off, 64);
    }
    if (j == 0) {
      const size_t base = ((size_t)r * NN + n0 + i) * 2;
      el[base + 0] = e0;
      el[base + 1] = e1;
      er[base + 0] = u0;
      er[base + 1] = u1;
    }
  }
}

// ---------------------------------------------------------------------------
// Fused pull + semantic logit: 256-thread block = 4 INDEPENDENT waves, one
// (r,n) each. Lane j owns cols 2j,2j+1 (head h=j>>5); f gathered as bf16x2.
// Wave-private LDS; no __syncthreads. Math bitwise = R16.
// ---------------------------------------------------------------------------
__global__ void __launch_bounds__(256) pull_semw(
    const int* __restrict__ starts,   // [3,NP1]
    const int* __restrict__ csrsrc,   // [3,E]
    const float* __restrict__ el,     // [3,N,2]
    const float* __restrict__ er,
    const unsigned short* __restrict__ fb,  // [3,N,128] bf16
    const float* __restrict__ b,      // [3,128]
    int do_relu,
    const float* __restrict__ aw1,    // [128,32]
    const float* __restrict__ ab1,    // [32]
    const float* __restrict__ aw2,    // [32]
    float* __restrict__ z,            // [3,N,128]
    float* __restrict__ wv) {         // [3,N]
  __shared__ float lz[4][FD];
  __shared__ float red[4][4][AH];
  __shared__ float wcol[4][AH];
  const int g = threadIdx.x >> 6;       // wave 0..3
  const int j = threadIdx.x & 63;       // lane
  const int rn = blockIdx.x * 4 + g;    // 0..59999 (grid exact)
  const int r = rn / NN;
  const int n = rn - r * NN;
  const int c = j * 2;
  const int h = j >> 5;
  const int* st = starts + r * NP1;
  const int* cs = csrsrc + (size_t)r * EE;
  const float* elr = el + (size_t)r * NN * 2;
  const unsigned short* fr = fb + (size_t)r * NN * FD;
  const int s0 = st[n], s1 = st[n + 1];
  const float ern = er[((size_t)r * NN + n) * 2 + h];

  float ax = 0.f, ay = 0.f, den = 0.f;
  int p = s0;
#define EDGE(iK)                                                        \
  {                                                                     \
    const int sK = cs[p + iK];                                          \
    const float wK = leaky_exp(elr[(size_t)sK * 2 + h] + ern);          \
    const unsigned int fvK = *(const unsigned int*)&fr[(size_t)sK * FD + c]; \
    den += wK;                                                          \
    ax += wK * bf2f((unsigned short)(fvK & 0xffff));                    \
    ay += wK * bf2f((unsigned short)(fvK >> 16));                       \
  }
  for (; p + 8 <= s1; p += 8) {
    EDGE(0) EDGE(1) EDGE(2) EDGE(3) EDGE(4) EDGE(5) EDGE(6) EDGE(7)
  }
  for (; p + 4 <= s1; p += 4) {
    EDGE(0) EDGE(1) EDGE(2) EDGE(3)
  }
  for (; p < s1; ++p) {
    EDGE(0)
  }
#undef EDGE

  const float inv = 1.f / fmaxf(den, 1e-9f);
  float vx = ax * inv + b[r * FD + c];
  float vy = ay * inv + b[r * FD + c + 1];
  if (do_relu) { vx = fmaxf(vx, 0.f); vy = fmaxf(vy, 0.f); }
  float2* zrow = (float2*)&z[(size_t)rn * FD];
  zrow[j] = make_float2(vx, vy);

  // ---- fused semantic-attention logit (wave-private LDS, wave-sync only) --
  lz[g][c] = vx;
  lz[g][c + 1] = vy;
  __builtin_amdgcn_wave_barrier();
  const int col = j & 31;
  const int p0 = j >> 5;  // 0..1; also handles p0+2
#pragma unroll
  for (int t = 0; t < 2; ++t) {
    const int part = p0 + 2 * t;
    float a2 = 0.f;
#pragma unroll
    for (int kk = 0; kk < 32; ++kk) {
      const int k = part * 32 + kk;
      a2 += lz[g][k] * aw1[(size_t)k * AH + col];
    }
    red[g][part][col] = a2;
  }
  __builtin_amdgcn_wave_barrier();
  if (j < 32)
    wcol[g][j] = tanhf(red[g][0][j] + red[g][1][j] + red[g][2][j] +
                       red[g][3][j] + ab1[j]) * aw2[j];
  __builtin_amdgcn_wave_barrier();
  if (j == 0) {
    float w = 0.f;
#pragma unroll
    for (int cix = 0; cix < AH; ++cix) w += wcol[g][cix];
    wv[rn] = w;
  }
}

// Fused reduce + beta
__global__ void reduce_beta(const float* __restrict__ wv, float* __restrict__ S) {
  __shared__ float p[256];
  const int t = threadIdx.x;
  float tot[RR];
  for (int r = 0; r < RR; ++r) {
    float s = 0.f;
    for (int n = t; n < NN; n += 256) s += wv[(size_t)r * NN + n];
    p[t] = s;
    __syncthreads();
    for (int off = 128; off > 0; off >>= 1) {
      if (t < off) p[t] += p[t + off];
      __syncthreads();
    }
    tot[r] = p[0];
    __syncthreads();
  }
  if (t == 0) {
    S[0] = tot[0]; S[1] = tot[1]; S[2] = tot[2];
    float w0 = tot[0] / (float)NN, w1 = tot[1] / (float)NN, w2 = tot[2] / (float)NN;
    float mx = fmaxf(w0, fmaxf(w1, w2));
    float e0 = __expf(w0 - mx), e1 = __expf(w1 - mx), e2 = __expf(w2 - mx);
    float inv = 1.f / (e0 + e1 + e2);
    S[4] = e0 * inv; S[5] = e1 * inv; S[6] = e2 * inv;
  }
}

__global__ void combine_f32(const float* __restrict__ z,
                            const float* __restrict__ S,
                            float* __restrict__ out) {
  const int idx = blockIdx.x * blockDim.x + threadIdx.x;
  if (idx >= NN * FD) return;
  out[idx] = S[4] * z[idx] + S[5] * z[(size_t)NN * FD + idx] +
             S[6] * z[2 * (size_t)NN * FD + idx];
}

// ------------------- fallback kernels (R10 CSR path, proven) ----------------
__global__ void gemm_el_er(const float* __restrict__ hin,
                           const float* __restrict__ W,
                           const float* __restrict__ al,
                           const float* __restrict__ ar,
                           float* __restrict__ f,
                           float* __restrict__ el,
                           float* __restrict__ er) {
  const int B8 = 8;
  __shared__ float lh[B8 * FD];
  const int j = threadIdx.x;
  const int n0 = blockIdx.x * B8;
#pragma unroll
  for (int i = 0; i < B8; ++i)
    lh[i * FD + j] = hin[(size_t)(n0 + i) * FD + j];
  __syncthreads();
  float acc[B8];
#pragma unroll
  for (int i = 0; i < B8; ++i) acc[i] = 0.f;
  for (int k = 0; k < FD; ++k) {
    const float w = W[(size_t)k * FD + j];
#pragma unroll
    for (int i = 0; i < B8; ++i) acc[i] += lh[i * FD + k] * w;
  }
  const float alv = al[j];
  const float arv = ar[j];
#pragma unroll
  for (int i = 0; i < B8; ++i) f[(size_t)(n0 + i) * FD + j] = acc[i];
  __syncthreads();
#pragma unroll
  for (int i = 0; i < B8; ++i) lh[i * FD + j] = acc[i] * alv;
  __syncthreads();
  if (j < B8 * 2) {
    const int i = j >> 1, h = j & 1;
    const float* p = &lh[i * FD + h * 64];
    float s = 0.f;
    for (int d = 0; d < 64; ++d) s += p[d];
    el[(size_t)(n0 + i) * 2 + h] = s;
  }
  __syncthreads();
#pragma unroll
  for (int i = 0; i < B8; ++i) lh[i * FD + j] = acc[i] * arv;
  __syncthreads();
  if (j < B8 * 2) {
    const int i = j >> 1, h = j & 1;
    const float* p = &lh[i * FD + h * 64];
    float s = 0.f;
    for (int d = 0; d < 64; ++d) s += p[d];
    er[(size_t)(n0 + i) * 2 + h] = s;
  }
}

__global__ void pull_aggr(const int* __restrict__ starts,
                          const int* __restrict__ csrsrc,
                          const float* __restrict__ el,
                          const float* __restrict__ er,
                          const float* __restrict__ f,
                          const float* __restrict__ b,
                          int do_relu,
                          float* __restrict__ z) {
  const int n = blockIdx.x;
  const int j = threadIdx.x;
  const int h = j >> 6;
  const int s0 = starts[n], s1 = starts[n + 1];
  const float ern = er[(size_t)n * 2 + h];
  float acc = 0.f, den = 0.f;
  for (int p = s0; p < s1; ++p) {
    const int src = csrsrc[p];
    const float w = leaky_exp(el[(size_t)src * 2 + h] + ern);
    den += w;
    acc += w * f[(size_t)src * FD + j];
  }
  float v = acc / fmaxf(den, 1e-9f) + b[j];
  if (do_relu) v = fmaxf(v, 0.f);
  z[(size_t)n * FD + j] = v;
}

__global__ void semw_nodes(const float* __restrict__ z,
                           const float* __restrict__ aw1,
                           const float* __restrict__ ab1,
                           const float* __restrict__ aw2,
                           float* __restrict__ wv) {
  __shared__ float lz[2][FD];
  __shared__ float red[2][4][AH];
  __shared__ float wcol[2][AH];
  const int g = threadIdx.x >> 7;
  const int t = threadIdx.x & 127;
  const int pair = blockIdx.x * 2 + g;
  const int n = pair / RR;
  const int r = pair - n * RR;
  lz[g][t] = z[((size_t)r * NN + n) * FD + t];
  __syncthreads();
  const int col = t & 31;
  const int part = t >> 5;
  float acc = 0.f;
#pragma unroll
  for (int kk = 0; kk < 32; ++kk) {
    const int k = part * 32 + kk;
    acc += lz[g][k] * aw1[(size_t)k * AH + col];
  }
  red[g][part][col] = acc;
  __syncthreads();
  if (part == 0) {
    float s = red[g][0][col] + red[g][1][col] + red[g][2][col] + red[g][3][col];
    wcol[g][col] = tanhf(s + ab1[col]) * aw2[col];
  }
  __syncthreads();
  if (t == 0) {
    float w = 0.f;
#pragma unroll
    for (int c = 0; c < AH; ++c) w += wcol[g][c];
    wv[(size_t)r * NN + n] = w;
  }
}

// ---------------------------------------------------------------------------
extern "C" void kernel_launch(void* const* d_in, const int* in_sizes, int n_in,
                              void* d_out, int out_size, void* d_ws, size_t ws_size,
                              hipStream_t stream) {
  const float* x   = (const float*)d_in[0];
  const int*   edg = (const int*)d_in[1];
  const float* W1  = (const float*)d_in[2];
  const float* al1 = (const float*)d_in[3];
  const float* ar1 = (const float*)d_in[4];
  const float* b1  = (const float*)d_in[5];
  const float* W2  = (const float*)d_in[6];
  const float* al2 = (const float*)d_in[7];
  const float* ar2 = (const float*)d_in[8];
  const float* b2  = (const float*)d_in[9];
  const float* aw1 = (const float*)d_in[10];
  const float* ab1 = (const float*)d_in[11];
  const float* aw2 = (const float*)d_in[12];
  const float* bw1 = (const float*)d_in[13];
  const float* bb1 = (const float*)d_in[14];
  const float* bw2 = (const float*)d_in[15];
  float* out = (float*)d_out;

  const size_t need_big = 67200128;  // gate proven on this ws
  if (ws_size >= need_big) {
    float* S      = (float*)d_ws;                    // 16
    float* wv     = S + 16;                          // RR*NN
    float* el     = wv + (size_t)RR * NN;            // RR*NN*2
    float* er     = el + (size_t)RR * NN * 2;        // RR*NN*2
    float* z      = er + (size_t)RR * NN * 2;        // RR*NN*FD fp32
    unsigned short* fb = (unsigned short*)(z + (size_t)RR * NN * FD);  // bf16
    int*   cnt    = (int*)(fb + (size_t)RR * NN * FD);  // RR*NN
    int*   starts = cnt + RR * NN;                   // RR*NP1
    int*   cursor = starts + RR * NP1;               // RR*NP1
    int*   csrsrc = cursor + RR * NP1;               // RR*EE

    hipMemsetAsync(cnt, 0, (size_t)RR * NN * sizeof(int), stream);
    csr_count<<<(RR * EE + 255) / 256, 256, 0, stream>>>(edg, cnt);
    csr_scan<<<RR, 256, 0, stream>>>(cnt, starts, cursor);
    csr_scatter<<<(RR * EE + 255) / 256, 256, 0, stream>>>(edg, cursor, csrsrc);

    const int gemmBlocks = (RR * (NN / BN) + 3) / 4;  // 938
    const int pullBlocks = RR * NN / 4;               // 15000

    // layer 1
    gemm_all<<<gemmBlocks, 256, 0, stream>>>(x, W1, al1, ar1, fb, el, er);
    pull_semw<<<pullBlocks, 256, 0, stream>>>(starts, csrsrc, el, er, fb, b1, 1,
                                              aw1, ab1, aw2, z, wv);
    reduce_beta<<<1, 256, 0, stream>>>(wv, S);
    combine_f32<<<(NN * FD + 255) / 256, 256, 0, stream>>>(z, S, out);  // hmid

    // layer 2
    gemm_all<<<gemmBlocks, 256, 0, stream>>>(out, W2, al2, ar2, fb, el, er);
    pull_semw<<<pullBlocks, 256, 0, stream>>>(starts, csrsrc, el, er, fb, b2, 0,
                                              bw1, bb1, bw2, z, wv);
    reduce_beta<<<1, 256, 0, stream>>>(wv, S);
    combine_f32<<<(NN * FD + 255) / 256, 256, 0, stream>>>(z, S, out);
    return;
  }

  // ---------------- fallback: R10 CSR path (46 MB, proven) ----------------
  float* S      = (float*)d_ws;
  float* wv     = S + 16;
  float* el     = wv + (size_t)RR * NN;
  float* er     = el + (size_t)NN * 2;
  float* f      = er + (size_t)NN * 2;
  float* z      = f + (size_t)NN * FD;
  int*   cnt    = (int*)(z + (size_t)RR * NN * FD);
  int*   starts = cnt + RR * NN;
  int*   cursor = starts + RR * NP1;
  int*   csrsrc = cursor + RR * NP1;

  hipMemsetAsync(cnt, 0, (size_t)RR * NN * sizeof(int), stream);
  csr_count<<<(RR * EE + 255) / 256, 256, 0, stream>>>(edg, cnt);
  csr_scan<<<RR, 256, 0, stream>>>(cnt, starts, cursor);
  csr_scatter<<<(RR * EE + 255) / 256, 256, 0, stream>>>(edg, cursor, csrsrc);

  for (int r = 0; r < RR; ++r) {
    gemm_el_er<<<NN / 8, 128, 0, stream>>>(
        x, W1 + (size_t)r * FD * FD, al1 + r * FD, ar1 + r * FD, f, el, er);
    pull_aggr<<<NN, 128, 0, stream>>>(starts + r * NP1, csrsrc + (size_t)r * EE,
                                      el, er, f, b1 + r * FD, 1,
                                      z + (size_t)r * NN * FD);
  }
  semw_nodes<<<NN * RR / 2, 256, 0, stream>>>(z, aw1, ab1, aw2, wv);
  reduce_beta<<<1, 256, 0, stream>>>(wv, S);
  combine_f32<<<(NN * FD + 255) / 256, 256, 0, stream>>>(z, S, out);

  for (int r = 0; r < RR; ++r) {
    gemm_el_er<<<NN / 8, 128, 0, stream>>>(
        out, W2 + (size_t)r * FD * FD, al2 + r * FD, ar2 + r * FD, f, el, er);
    pull_aggr<<<NN, 128, 0, stream>>>(starts + r * NP1, csrsrc + (size_t)r * EE,
                                      el, er, f, b2 + r * FD, 0,
                                      z + (size_t)r * NN * FD);
  }
  semw_nodes<<<NN * RR / 2, 256, 0, stream>>>(z, bw1, bb1, bw2, wv);
  reduce_beta<<<1, 256, 0, stream>>>(wv, S);
  combine_f32<<<(NN * FD + 255) / 256, 256, 0, stream>>>(z, S, out);
}

// Round 19
// 640.226 us; speedup vs baseline: 1.0257x; 1.0182x over previous
//
#include <hip/hip_runtime.h>
#include <hip/hip_bf16.h>

// Established facts (R3-R18): d_in = setup_inputs() dict order; floats fp32;
// edges int32; output fp32 [20000,128]. Best = R16 615.7us (64-thr waves,
// bf16 f). R17/R18: all occupancy-repack attempts regressed (36-41% occ is
// structural). This round: revert to R16 base; cut per-edge VALU via CSR-
// ordered wexp precompute (scalar loads in pull); fuse L1-combine into L2-gemm.
#define NN 20000
#define RR 3
#define EE 320000
#define FD 128
#define AH 32
#define NP1 (NN + 1)
#define NEG_SLOPE 0.2f

__device__ __forceinline__ int clamp_idx(int v) {
  v = v < 0 ? 0 : v;
  return v < NN ? v : NN - 1;
}
__device__ __forceinline__ float leaky_exp(float e) {
  e = e > 0.f ? e : NEG_SLOPE * e;
  return __expf(e);
}
__device__ __forceinline__ float bf2f(unsigned short u) {
  union { unsigned int i; float f; } c;
  c.i = ((unsigned int)u) << 16;
  return c.f;
}
// fp32 -> bf16 round-to-nearest-even
__device__ __forceinline__ unsigned short f2bf(float v) {
  union { float f; unsigned int i; } c;
  c.f = v;
  const unsigned int u = c.i;
  return (unsigned short)((u + 0x7fffu + ((u >> 16) & 1u)) >> 16);
}

// ----------------------------- CSR build -----------------------------------
__global__ void csr_count(const int* __restrict__ edg, int* __restrict__ cnt) {
  const int idx = blockIdx.x * blockDim.x + threadIdx.x;
  if (idx >= RR * EE) return;
  const int r = idx / EE, k = idx - r * EE;
  const int dst = clamp_idx(edg[(size_t)r * 2 * EE + EE + k]);
  atomicAdd(&cnt[r * NN + dst], 1);
}

__global__ void csr_scan(const int* __restrict__ cnt, int* __restrict__ starts,
                         int* __restrict__ cursor) {
  __shared__ int part[256];
  const int r = blockIdx.x, t = threadIdx.x;
  const int CH = (NN + 255) / 256;  // 79
  const int lo = t * CH, hi = min(lo + CH, NN);
  int s = 0;
  for (int i = lo; i < hi; ++i) s += cnt[r * NN + i];
  part[t] = s;
  __syncthreads();
  if (t == 0) {
    int run = 0;
    for (int i = 0; i < 256; ++i) { const int v = part[i]; part[i] = run; run += v; }
  }
  __syncthreads();
  int run = part[t];
  for (int i = lo; i < hi; ++i) {
    starts[r * NP1 + i] = run;
    cursor[r * NP1 + i] = run;
    run += cnt[r * NN + i];
  }
  if (t == 255) starts[r * NP1 + NN] = run;
}

// Scatter also records dst per CSR slot (for the wexp precompute).
__global__ void csr_scatter(const int* __restrict__ edg, int* __restrict__ cursor,
                            int* __restrict__ csrsrc, int* __restrict__ wdst) {
  const int idx = blockIdx.x * blockDim.x + threadIdx.x;
  if (idx >= RR * EE) return;
  const int r = idx / EE, k = idx - r * EE;
  const int src = clamp_idx(edg[(size_t)r * 2 * EE + k]);
  const int dst = clamp_idx(edg[(size_t)r * 2 * EE + EE + k]);
  const int pos = atomicAdd(&cursor[r * NP1 + dst], 1);
  csrsrc[(size_t)r * EE + pos] = src;
  wdst[(size_t)r * EE + pos] = dst;
}

// Per-edge softmax weights, CSR order: wexp[p] = (w_h0, w_h1) as float2.
__global__ void wexp_all(const int* __restrict__ csrsrc,
                         const int* __restrict__ wdst,
                         const float* __restrict__ el,   // [3,N,2]
                         const float* __restrict__ er,
                         float2* __restrict__ wexp) {    // [3*E]
  const int i = blockIdx.x * blockDim.x + threadIdx.x;
  if (i >= RR * EE) return;
  const int r = i / EE;
  const int src = csrsrc[i];
  const int dst = wdst[i];
  const float2 l = *(const float2*)&el[((size_t)r * NN + src) * 2];
  const float2 u = *(const float2*)&er[((size_t)r * NN + dst) * 2];
  wexp[i] = make_float2(leaky_exp(l.x + u.x), leaky_exp(l.y + u.y));
}

// ---------------------------------------------------------------------------
// Merged gemm (R16-exact): block = 1 wave, BN=16 nodes, lane j owns cols
// j (head 0) and j+64 (head 1); el/er via shfl; f stored bf16.
// ---------------------------------------------------------------------------
#define BN 16
__global__ void __launch_bounds__(64, 4) gemm_all(
    const float* __restrict__ hin,            // [N,128]
    const float* __restrict__ W,              // [3,128,128]
    const float* __restrict__ al,             // [3,128]
    const float* __restrict__ ar,             // [3,128]
    unsigned short* __restrict__ fb,          // [3,N,128] bf16
    float* __restrict__ el,                   // [3,N,2]
    float* __restrict__ er) {
  __shared__ float lh[BN * FD];  // 8 KB
  const int blocksPerRel = NN / BN;  // 1250
  const int r = blockIdx.x / blocksPerRel;
  const int n0 = (blockIdx.x % blocksPerRel) * BN;
  const int j = threadIdx.x;  // 0..63

  {
    const float4* s4 = (const float4*)&hin[(size_t)n0 * FD];
    float4* d4 = (float4*)lh;
#pragma unroll
    for (int t = 0; t < 8; ++t) d4[j + 64 * t] = s4[j + 64 * t];
  }
  __syncthreads();

  const float* Wr = W + (size_t)r * FD * FD;
  float acc0[BN], acc1[BN];
#pragma unroll
  for (int i = 0; i < BN; ++i) { acc0[i] = 0.f; acc1[i] = 0.f; }

  for (int k4 = 0; k4 < FD; k4 += 4) {
    const float wa0 = Wr[(size_t)(k4 + 0) * FD + j];
    const float wb0 = Wr[(size_t)(k4 + 0) * FD + j + 64];
    const float wa1 = Wr[(size_t)(k4 + 1) * FD + j];
    const float wb1 = Wr[(size_t)(k4 + 1) * FD + j + 64];
    const float wa2 = Wr[(size_t)(k4 + 2) * FD + j];
    const float wb2 = Wr[(size_t)(k4 + 2) * FD + j + 64];
    const float wa3 = Wr[(size_t)(k4 + 3) * FD + j];
    const float wb3 = Wr[(size_t)(k4 + 3) * FD + j + 64];
#pragma unroll
    for (int i = 0; i < BN; ++i) {
      const float4 h4 = *(const float4*)&lh[i * FD + k4];
      acc0[i] = fmaf(h4.x, wa0, fmaf(h4.y, wa1, fmaf(h4.z, wa2, fmaf(h4.w, wa3, acc0[i]))));
      acc1[i] = fmaf(h4.x, wb0, fmaf(h4.y, wb1, fmaf(h4.z, wb2, fmaf(h4.w, wb3, acc1[i]))));
    }
  }

  const float al0 = al[r * FD + j];
  const float al1v = al[r * FD + j + 64];
  const float ar0 = ar[r * FD + j];
  const float ar1v = ar[r * FD + j + 64];

#pragma unroll
  for (int i = 0; i < BN; ++i) {
    const size_t row = ((size_t)r * NN + n0 + i) * FD;
    fb[row + j] = f2bf(acc0[i]);
    fb[row + j + 64] = f2bf(acc1[i]);
    float e0 = acc0[i] * al0;
    float e1 = acc1[i] * al1v;
    float u0 = acc0[i] * ar0;
    float u1 = acc1[i] * ar1v;
#pragma unroll
    for (int off = 32; off > 0; off >>= 1) {
      e0 += __shfl_down(e0, off, 64);
      e1 += __shfl_down(e1, off, 64);
      u0 += __shfl_down(u0, off, 64);
      u1 += __shfl_down(u1, off, 64);
    }
    if (j == 0) {
      const size_t base = ((size_t)r * NN + n0 + i) * 2;
      el[base + 0] = e0;
      el[base + 1] = e1;
      er[base + 0] = u0;
      er[base + 1] = u1;
    }
  }
}

// Layer-2 gemm with the layer-1 combine fused into LDS staging:
// hin row = S4*z0 + S5*z1 + S6*z2 (identical arithmetic to combine_f32).
__global__ void __launch_bounds__(64, 4) gemm_all2(
    const float* __restrict__ z,              // [3,N,128] (layer-1 z)
    const float* __restrict__ Sp,             // beta at Sp[4..6]
    const float* __restrict__ W,
    const float* __restrict__ al,
    const float* __restrict__ ar,
    unsigned short* __restrict__ fb,
    float* __restrict__ el,
    float* __restrict__ er) {
  __shared__ float lh[BN * FD];
  const int blocksPerRel = NN / BN;
  const int r = blockIdx.x / blocksPerRel;
  const int n0 = (blockIdx.x % blocksPerRel) * BN;
  const int j = threadIdx.x;

  {
    const float s4v = Sp[4], s5v = Sp[5], s6v = Sp[6];
    const float4* z0 = (const float4*)&z[(size_t)(0 * NN + n0) * FD];
    const float4* z1 = (const float4*)&z[(size_t)(1 * NN + n0) * FD];
    const float4* z2 = (const float4*)&z[(size_t)(2 * NN + n0) * FD];
    float4* d4 = (float4*)lh;
#pragma unroll
    for (int t = 0; t < 8; ++t) {
      const int ix = j + 64 * t;
      const float4 a = z0[ix], b = z1[ix], cc = z2[ix];
      d4[ix] = make_float4(s4v * a.x + s5v * b.x + s6v * cc.x,
                           s4v * a.y + s5v * b.y + s6v * cc.y,
                           s4v * a.z + s5v * b.z + s6v * cc.z,
                           s4v * a.w + s5v * b.w + s6v * cc.w);
    }
  }
  __syncthreads();

  const float* Wr = W + (size_t)r * FD * FD;
  float acc0[BN], acc1[BN];
#pragma unroll
  for (int i = 0; i < BN; ++i) { acc0[i] = 0.f; acc1[i] = 0.f; }

  for (int k4 = 0; k4 < FD; k4 += 4) {
    const float wa0 = Wr[(size_t)(k4 + 0) * FD + j];
    const float wb0 = Wr[(size_t)(k4 + 0) * FD + j + 64];
    const float wa1 = Wr[(size_t)(k4 + 1) * FD + j];
    const float wb1 = Wr[(size_t)(k4 + 1) * FD + j + 64];
    const float wa2 = Wr[(size_t)(k4 + 2) * FD + j];
    const float wb2 = Wr[(size_t)(k4 + 2) * FD + j + 64];
    const float wa3 = Wr[(size_t)(k4 + 3) * FD + j];
    const float wb3 = Wr[(size_t)(k4 + 3) * FD + j + 64];
#pragma unroll
    for (int i = 0; i < BN; ++i) {
      const float4 h4 = *(const float4*)&lh[i * FD + k4];
      acc0[i] = fmaf(h4.x, wa0, fmaf(h4.y, wa1, fmaf(h4.z, wa2, fmaf(h4.w, wa3, acc0[i]))));
      acc1[i] = fmaf(h4.x, wb0, fmaf(h4.y, wb1, fmaf(h4.z, wb2, fmaf(h4.w, wb3, acc1[i]))));
    }
  }

  const float al0 = al[r * FD + j];
  const float al1v = al[r * FD + j + 64];
  const float ar0 = ar[r * FD + j];
  const float ar1v = ar[r * FD + j + 64];

#pragma unroll
  for (int i = 0; i < BN; ++i) {
    const size_t row = ((size_t)r * NN + n0 + i) * FD;
    fb[row + j] = f2bf(acc0[i]);
    fb[row + j + 64] = f2bf(acc1[i]);
    float e0 = acc0[i] * al0;
    float e1 = acc1[i] * al1v;
    float u0 = acc0[i] * ar0;
    float u1 = acc1[i] * ar1v;
#pragma unroll
    for (int off = 32; off > 0; off >>= 1) {
      e0 += __shfl_down(e0, off, 64);
      e1 += __shfl_down(e1, off, 64);
      u0 += __shfl_down(u0, off, 64);
      u1 += __shfl_down(u1, off, 64);
    }
    if (j == 0) {
      const size_t base = ((size_t)r * NN + n0 + i) * 2;
      el[base + 0] = e0;
      el[base + 1] = e1;
      er[base + 0] = u0;
      er[base + 1] = u1;
    }
  }
}

// ---------------------------------------------------------------------------
// Fused pull + semantic logit (R16 structure): block = 1 wave, lane j owns
// cols 2j,2j+1 (head h=j>>5). Edge weights come precomputed from wexp[]
// (wave-uniform scalar loads) -- per-edge VALU drops ~14 -> ~9 ops and the
// per-lane el-gather disappears. Accumulation order unchanged (bitwise=R16).
// ---------------------------------------------------------------------------
__global__ void __launch_bounds__(64, 4) pull_semw(
    const int* __restrict__ starts,   // [3,NP1]
    const int* __restrict__ csrsrc,   // [3,E]
    const float2* __restrict__ wexp,  // [3*E] per-edge weights (h0,h1)
    const unsigned short* __restrict__ fb,  // [3,N,128] bf16
    const float* __restrict__ b,      // [3,128]
    int do_relu,
    const float* __restrict__ aw1,    // [128,32]
    const float* __restrict__ ab1,    // [32]
    const float* __restrict__ aw2,    // [32]
    float* __restrict__ z,            // [3,N,128]
    float* __restrict__ wv) {         // [3,N]
  __shared__ float lz[FD];
  __shared__ float red[4][AH];
  __shared__ float wcol[AH];
  const int rn = blockIdx.x;
  const int r = rn / NN;
  const int n = rn - r * NN;
  const int j = threadIdx.x;       // 0..63
  const int c = j * 2;
  const int h = j >> 5;
  const int* st = starts + r * NP1;
  const int* cs = csrsrc + (size_t)r * EE;
  const float2* wx = wexp + (size_t)r * EE;
  const unsigned short* fr = fb + (size_t)r * NN * FD;
  const int s0 = st[n], s1 = st[n + 1];

  float ax = 0.f, ay = 0.f, den = 0.f;
  int p = s0;
#define EDGE(iK)                                                        \
  {                                                                     \
    const int sK = cs[p + iK];                                          \
    const float2 w2K = wx[p + iK];                                      \
    const float wK = h ? w2K.y : w2K.x;                                 \
    const unsigned int fvK = *(const unsigned int*)&fr[(size_t)sK * FD + c]; \
    den += wK;                                                          \
    ax += wK * bf2f((unsigned short)(fvK & 0xffff));                    \
    ay += wK * bf2f((unsigned short)(fvK >> 16));                       \
  }
  for (; p + 8 <= s1; p += 8) {
    EDGE(0) EDGE(1) EDGE(2) EDGE(3) EDGE(4) EDGE(5) EDGE(6) EDGE(7)
  }
  for (; p + 4 <= s1; p += 4) {
    EDGE(0) EDGE(1) EDGE(2) EDGE(3)
  }
  for (; p < s1; ++p) {
    EDGE(0)
  }
#undef EDGE

  const float inv = 1.f / fmaxf(den, 1e-9f);
  float vx = ax * inv + b[r * FD + c];
  float vy = ay * inv + b[r * FD + c + 1];
  if (do_relu) { vx = fmaxf(vx, 0.f); vy = fmaxf(vy, 0.f); }
  float2* zrow = (float2*)&z[(size_t)rn * FD];
  zrow[j] = make_float2(vx, vy);

  // ---- fused semantic-attention logit ----
  lz[c] = vx;
  lz[c + 1] = vy;
  __syncthreads();
  const int col = j & 31;
  const int p0 = j >> 5;
#pragma unroll
  for (int t = 0; t < 2; ++t) {
    const int part = p0 + 2 * t;
    float a2 = 0.f;
#pragma unroll
    for (int kk = 0; kk < 32; ++kk) {
      const int k = part * 32 + kk;
      a2 += lz[k] * aw1[(size_t)k * AH + col];
    }
    red[part][col] = a2;
  }
  __syncthreads();
  if (j < 32)
    wcol[j] = tanhf(red[0][j] + red[1][j] + red[2][j] + red[3][j] + ab1[j]) *
              aw2[j];
  __syncthreads();
  if (j == 0) {
    float w = 0.f;
#pragma unroll
    for (int cix = 0; cix < AH; ++cix) w += wcol[cix];
    wv[rn] = w;
  }
}

// Fused reduce + beta
__global__ void reduce_beta(const float* __restrict__ wv, float* __restrict__ S) {
  __shared__ float p[256];
  const int t = threadIdx.x;
  float tot[RR];
  for (int r = 0; r < RR; ++r) {
    float s = 0.f;
    for (int n = t; n < NN; n += 256) s += wv[(size_t)r * NN + n];
    p[t] = s;
    __syncthreads();
    for (int off = 128; off > 0; off >>= 1) {
      if (t < off) p[t] += p[t + off];
      __syncthreads();
    }
    tot[r] = p[0];
    __syncthreads();
  }
  if (t == 0) {
    S[0] = tot[0]; S[1] = tot[1]; S[2] = tot[2];
    float w0 = tot[0] / (float)NN, w1 = tot[1] / (float)NN, w2 = tot[2] / (float)NN;
    float mx = fmaxf(w0, fmaxf(w1, w2));
    float e0 = __expf(w0 - mx), e1 = __expf(w1 - mx), e2 = __expf(w2 - mx);
    float inv = 1.f / (e0 + e1 + e2);
    S[4] = e0 * inv; S[5] = e1 * inv; S[6] = e2 * inv;
  }
}

__global__ void combine_f32(const float* __restrict__ z,
                            const float* __restrict__ S,
                            float* __restrict__ out) {
  const int idx = blockIdx.x * blockDim.x + threadIdx.x;
  if (idx >= NN * FD) return;
  out[idx] = S[4] * z[idx] + S[5] * z[(size_t)NN * FD + idx] +
             S[6] * z[2 * (size_t)NN * FD + idx];
}

// ---------------------------------------------------------------------------
extern "C" void kernel_launch(void* const* d_in, const int* in_sizes, int n_in,
                              void* d_out, int out_size, void* d_ws, size_t ws_size,
                              hipStream_t stream) {
  const float* x   = (const float*)d_in[0];
  const int*   edg = (const int*)d_in[1];
  const float* W1  = (const float*)d_in[2];
  const float* al1 = (const float*)d_in[3];
  const float* ar1 = (const float*)d_in[4];
  const float* b1  = (const float*)d_in[5];
  const float* W2  = (const float*)d_in[6];
  const float* al2 = (const float*)d_in[7];
  const float* ar2 = (const float*)d_in[8];
  const float* b2  = (const float*)d_in[9];
  const float* aw1 = (const float*)d_in[10];
  const float* ab1 = (const float*)d_in[11];
  const float* aw2 = (const float*)d_in[12];
  const float* bw1 = (const float*)d_in[13];
  const float* bb1 = (const float*)d_in[14];
  const float* bw2 = (const float*)d_in[15];
  float* out = (float*)d_out;

  // Layout (fits well under the proven 67.2MB):
  // S | wv | el | er | z(fp32) | fb(bf16) | wexp(float2) | cnt starts cursor csrsrc wdst
  float* S      = (float*)d_ws;                    // 16
  float* wv     = S + 16;                          // RR*NN
  float* el     = wv + (size_t)RR * NN;            // RR*NN*2
  float* er     = el + (size_t)RR * NN * 2;        // RR*NN*2
  float* z      = er + (size_t)RR * NN * 2;        // RR*NN*FD fp32
  unsigned short* fb = (unsigned short*)(z + (size_t)RR * NN * FD);  // bf16
  float2* wexp  = (float2*)(fb + (size_t)RR * NN * FD);  // RR*EE float2
  int*   cnt    = (int*)(wexp + (size_t)RR * EE);  // RR*NN
  int*   starts = cnt + RR * NN;                   // RR*NP1
  int*   cursor = starts + RR * NP1;               // RR*NP1
  int*   csrsrc = cursor + RR * NP1;               // RR*EE
  int*   wdst   = csrsrc + (size_t)RR * EE;        // RR*EE

  hipMemsetAsync(cnt, 0, (size_t)RR * NN * sizeof(int), stream);
  csr_count<<<(RR * EE + 255) / 256, 256, 0, stream>>>(edg, cnt);
  csr_scan<<<RR, 256, 0, stream>>>(cnt, starts, cursor);
  csr_scatter<<<(RR * EE + 255) / 256, 256, 0, stream>>>(edg, cursor, csrsrc, wdst);

  // ---------------- layer 1 ----------------
  gemm_all<<<RR * (NN / BN), 64, 0, stream>>>(x, W1, al1, ar1, fb, el, er);
  wexp_all<<<(RR * EE + 255) / 256, 256, 0, stream>>>(csrsrc, wdst, el, er, wexp);
  pull_semw<<<RR * NN, 64, 0, stream>>>(starts, csrsrc, wexp, fb, b1, 1,
                                        aw1, ab1, aw2, z, wv);
  reduce_beta<<<1, 256, 0, stream>>>(wv, S);

  // ---------------- layer 2 (L1-combine fused into gemm staging) ----------
  gemm_all2<<<RR * (NN / BN), 64, 0, stream>>>(z, S, W2, al2, ar2, fb, el, er);
  wexp_all<<<(RR * EE + 255) / 256, 256, 0, stream>>>(csrsrc, wdst, el, er, wexp);
  pull_semw<<<RR * NN, 64, 0, stream>>>(starts, csrsrc, wexp, fb, b2, 0,
                                        bw1, bb1, bw2, z, wv);
  reduce_beta<<<1, 256, 0, stream>>>(wv, S);
  combine_f32<<<(NN * FD + 255) / 256, 256, 0, stream>>>(z, S, out);
}